// Round 4
// baseline (37.690 us; speedup 1.0000x reference)
//
#include <hip/hip_runtime.h>
#include <hip/hip_bf16.h>
#include <string.h>

#define NUM_CLASS 4096
#define HIDDEN    512
#define NGROUPS   64
#define BATCH     64

// ws layout (int offsets):
//   [0..1]            nwork[2]
//   [16..271]         work[2][128] packed (g<<20)|(ncls<<12)|c0
//   [2048..10239]     srcoff[2][4096]  = widx*4096 + slot
//   [10240..18431]    inv[2][4096]     (scatter fallback only)
//   float idx 32768+: tmp[kh][h][widx<128][64b][64slot]
#define WS_NWORK 0
#define WS_WORK  16
#define WS_SRC   2048
#define WS_INV   10240
#define TMP_OFF_F 32768
#define TMP_H_STRIDE (128*4096)      // floats per (kh,h) slice
#define TMP_S_STRIDE (2*128*4096)    // floats per kh step

typedef __attribute__((ext_vector_type(8))) short short8;
typedef __attribute__((ext_vector_type(4))) float f32x4;

__device__ __forceinline__ unsigned int pack2bf(float a, float b) {
    __hip_bfloat16 ha = __float2bfloat16(a), hb = __float2bfloat16(b);
    unsigned short ua, ub;
    memcpy(&ua, &ha, 2); memcpy(&ub, &hb, 2);
    return (unsigned int)ua | ((unsigned int)ub << 16);
}

__global__ __launch_bounds__(1024) void prep_kernel(
    const int* __restrict__ co_gof, const int* __restrict__ cl_gof,
    const int* __restrict__ co_idx, const int* __restrict__ cl_idx,
    int* __restrict__ ws)
{
    __shared__ int s_starts[2][65];
    __shared__ int s_wbase[2][64];
    int tid = threadIdx.x;
    for (int v = tid; v < 2 * NUM_CLASS; v += 1024) {
        int h = v >> 12, c = v & (NUM_CLASS - 1);
        const int* gof = h ? cl_gof : co_gof;
        int g = gof[c];
        if (c == 0) { s_starts[h][0] = 0; s_starts[h][64] = NUM_CLASS; }
        else if (g != gof[c - 1]) s_starts[h][g] = c;
    }
    __syncthreads();
    if (tid < 64) {
        int lane = tid;
        for (int h = 0; h < 2; ++h) {
            int s = s_starts[h][lane], e = s_starts[h][lane + 1];
            int cnt = (e - s + 63) >> 6;
            int inc = cnt;
            #pragma unroll
            for (int d = 1; d < 64; d <<= 1) {
                int o = __shfl_up(inc, d, 64);
                if (lane >= d) inc += o;
            }
            int excl = inc - cnt;
            s_wbase[h][lane] = excl;
            for (int t = 0; t < cnt; ++t) {
                int c0 = s + t * 64;
                int ncls = min(64, e - c0);
                ws[WS_WORK + h * 128 + excl + t] = (lane << 20) | (ncls << 12) | c0;
            }
            if (lane == 63) ws[WS_NWORK + h] = inc;
        }
    }
    __syncthreads();
    for (int v = tid; v < 2 * NUM_CLASS; v += 1024) {
        int h = v >> 12, c = v & (NUM_CLASS - 1);
        const int* gof = h ? cl_gof : co_gof;
        const int* idx = h ? cl_idx : co_idx;
        int g = gof[c];
        int rel = c - s_starts[h][g];
        ws[WS_SRC + v] = (s_wbase[h][g] + (rel >> 6)) * 4096 + (rel & 63);
        ws[WS_INV + h * NUM_CLASS + idx[c]] = c;
    }
}

// KS in {1,2,4}: K split across blockIdx.z. SCATTER: direct permuted out (+bias).
template<int KS, bool SCATTER>
__global__ __launch_bounds__(256, 4) void gwl_stage1(
    const float* __restrict__ x,
    const float* __restrict__ co_W, const float* __restrict__ cl_W,
    const float* __restrict__ co_b, const float* __restrict__ cl_b,
    int* __restrict__ ws, float* __restrict__ out)
{
    int widx = blockIdx.x, h = blockIdx.y, kh = blockIdx.z;
    int nw = ws[WS_NWORK + h];
    if (widx >= nw) return;
    int packed = ws[WS_WORK + h * 128 + widx];
    int c0 = packed & 0xFFF, ncls = (packed >> 12) & 0xFF, g = packed >> 20;
    const float* Wp = h ? cl_W : co_W;
    int xrow = h * 64 + g;

    __shared__ __align__(16) unsigned char smem[18432];
    unsigned short (*Xs)[72]  = (unsigned short(*)[72])smem;
    unsigned short (*Wls)[72] = (unsigned short(*)[72])(smem + 9216);

    int tid = threadIdx.x;
    int l = tid & 63, w = tid >> 6;

    int rowq[4], kvq[4], wcl[4];
    #pragma unroll
    for (int q = 0; q < 4; ++q) {
        int v = q * 256 + tid;
        rowq[q] = v >> 4;
        kvq[q]  = v & 15;
        wcl[q]  = min(rowq[q], ncls - 1);
    }

    float4 rx[4], rw[4];
    f32x4 acc[4];
    #pragma unroll
    for (int i = 0; i < 4; ++i) acc[i] = (f32x4)(0.0f);

    const int NCH = 8 / KS;
    const int kbase = kh * (HIDDEN / KS);

#define LOADC(K0) do {                                                              \
    int k0_ = (K0);                                                                 \
    _Pragma("unroll")                                                               \
    for (int q = 0; q < 4; ++q) {                                                   \
        rx[q] = *(const float4*)(x + rowq[q] * 65536 + xrow * 512 + k0_ + kvq[q]*4);\
        rw[q] = *(const float4*)(Wp + (c0 + wcl[q]) * 512 + k0_ + kvq[q] * 4);      \
    } } while (0)

#define STOREC() do {                                                               \
    _Pragma("unroll")                                                               \
    for (int q = 0; q < 4; ++q) {                                                   \
        unsigned int x0 = pack2bf(rx[q].x, rx[q].y);                                \
        unsigned int x1 = pack2bf(rx[q].z, rx[q].w);                                \
        unsigned int w0 = pack2bf(rw[q].x, rw[q].y);                                \
        unsigned int w1 = pack2bf(rw[q].z, rw[q].w);                                \
        *(uint2*)&Xs[rowq[q]][kvq[q] * 4]  = make_uint2(x0, x1);                    \
        *(uint2*)&Wls[rowq[q]][kvq[q] * 4] = make_uint2(w0, w1);                    \
    } } while (0)

#define COMPUTEC() do {                                                             \
    _Pragma("unroll")                                                               \
    for (int kq = 0; kq < 2; ++kq) {                                                \
        int koff = kq * 32 + (l >> 4) * 8;                                          \
        short8 bfrag = *(const short8*)&Wls[w * 16 + (l & 15)][koff];               \
        _Pragma("unroll")                                                           \
        for (int i = 0; i < 4; ++i) {                                               \
            short8 afrag = *(const short8*)&Xs[16 * i + (l & 15)][koff];            \
            acc[i] = __builtin_amdgcn_mfma_f32_16x16x32_bf16(afrag, bfrag, acc[i],  \
                                                             0, 0, 0);              \
        }                                                                           \
    } } while (0)

    LOADC(kbase);
    #pragma unroll 1
    for (int t = 0; t < NCH; ++t) {
        STOREC();
        __syncthreads();
        if (t + 1 < NCH) LOADC(kbase + (t + 1) * 64);
        COMPUTEC();
        __syncthreads();
    }

    // epilogue: acc -> LDS f32 tile -> dense coalesced writes
    float (*ftile)[68] = (float(*)[68])smem;   // 64*68*4 = 17408 <= 18432
    #pragma unroll
    for (int i = 0; i < 4; ++i)
        #pragma unroll
        for (int r = 0; r < 4; ++r)
            ftile[16 * i + (l >> 4) * 4 + r][w * 16 + (l & 15)] = acc[i][r];
    __syncthreads();

    if (!SCATTER) {
        float* tile = (float*)ws + TMP_OFF_F
                    + (size_t)(kh * 2 + h) * TMP_H_STRIDE + (size_t)widx * 4096;
        #pragma unroll
        for (int p = 0; p < 4; ++p) {
            int row = p * 16 + (tid >> 4);
            int c4  = (tid & 15) * 4;
            *(float4*)&tile[row * 64 + c4] = *(const float4*)&ftile[row][c4];
        }
    } else {
        const float* bias = h ? cl_b : co_b;
        const int*   inv  = ws + WS_INV + h * NUM_CLASS;
        float* outh = out + (size_t)h * BATCH * NUM_CLASS;
        #pragma unroll
        for (int p = 0; p < 4; ++p) {
            int row = p * 16 + (tid >> 4);
            int c4  = (tid & 15) * 4;
            float4 v = *(const float4*)&ftile[row][c4];
            const float* ve = (const float*)&v;
            #pragma unroll
            for (int e = 0; e < 4; ++e) {
                int slot = c4 + e;
                if (slot < ncls) {
                    int c = c0 + slot;
                    outh[row * 4096 + inv[c]] = ve[e] + bias[c];
                }
            }
        }
    }
#undef LOADC
#undef STOREC
#undef COMPUTEC
}

template<int KS>
__global__ __launch_bounds__(256) void gwl_permute(
    const int* __restrict__ ws,
    const float* __restrict__ co_b, const float* __restrict__ cl_b,
    const int* __restrict__ co_idx, const int* __restrict__ cl_idx,
    float* __restrict__ out)
{
    int jh = blockIdx.x;   // 0..1
    int b  = blockIdx.y;   // 0..63
    int h  = blockIdx.z;   // 0..1
    const float* bias = h ? cl_b : co_b;
    const int*   idx  = h ? cl_idx : co_idx;
    const int* srcoff = ws + WS_SRC + h * NUM_CLASS;
    const float* tmpb = (const float*)ws + TMP_OFF_F
                      + (size_t)h * TMP_H_STRIDE + (size_t)b * 64;
    float* orow = out + ((size_t)h * 64 + b) * 4096;
    int tid = threadIdx.x;
    #pragma unroll
    for (int u = 0; u < 8; ++u) {
        int j = jh * 2048 + u * 256 + tid;
        int c = idx[j];
        int so = srcoff[c];
        float v = bias[c];
        #pragma unroll
        for (int s = 0; s < KS; ++s)
            v += tmpb[(size_t)s * TMP_S_STRIDE + so];
        orow[j] = v;
    }
}

extern "C" void kernel_launch(void* const* d_in, const int* in_sizes, int n_in,
                              void* d_out, int out_size, void* d_ws, size_t ws_size,
                              hipStream_t stream)
{
    (void)in_sizes; (void)n_in; (void)out_size;
    const float* x      = (const float*)d_in[0];
    const float* co_W   = (const float*)d_in[1];
    const float* cl_W   = (const float*)d_in[2];
    const float* co_b   = (const float*)d_in[3];
    const float* cl_b   = (const float*)d_in[4];
    const int*   co_gof = (const int*)d_in[5];
    const int*   cl_gof = (const int*)d_in[6];
    const int*   co_idx = (const int*)d_in[7];
    const int*   cl_idx = (const int*)d_in[8];
    int*   ws  = (int*)d_ws;
    float* out = (float*)d_out;

    hipLaunchKernelGGL(prep_kernel, dim3(1), dim3(1024), 0, stream,
                       co_gof, cl_gof, co_idx, cl_idx, ws);

    const size_t base  = (size_t)TMP_OFF_F * 4;
    const size_t slice = (size_t)TMP_S_STRIDE * 4;   // 4 MiB per kh step
    if (ws_size >= base + 4 * slice) {
        hipLaunchKernelGGL((gwl_stage1<4, false>), dim3(128, 2, 4), dim3(256), 0, stream,
                           x, co_W, cl_W, co_b, cl_b, ws, out);
        hipLaunchKernelGGL((gwl_permute<4>), dim3(2, 64, 2), dim3(256), 0, stream,
                           ws, co_b, cl_b, co_idx, cl_idx, out);
    } else if (ws_size >= base + 2 * slice) {
        hipLaunchKernelGGL((gwl_stage1<2, false>), dim3(128, 2, 2), dim3(256), 0, stream,
                           x, co_W, cl_W, co_b, cl_b, ws, out);
        hipLaunchKernelGGL((gwl_permute<2>), dim3(2, 64, 2), dim3(256), 0, stream,
                           ws, co_b, cl_b, co_idx, cl_idx, out);
    } else if (ws_size >= base + 1 * slice) {
        hipLaunchKernelGGL((gwl_stage1<1, false>), dim3(128, 2, 1), dim3(256), 0, stream,
                           x, co_W, cl_W, co_b, cl_b, ws, out);
        hipLaunchKernelGGL((gwl_permute<1>), dim3(2, 64, 2), dim3(256), 0, stream,
                           ws, co_b, cl_b, co_idx, cl_idx, out);
    } else {
        hipLaunchKernelGGL((gwl_stage1<1, true>), dim3(128, 2, 1), dim3(256), 0, stream,
                           x, co_W, cl_W, co_b, cl_b, ws, out);
    }
}

// Round 5
// 24.910 us; speedup vs baseline: 1.5130x; 1.5130x over previous
//
#include <hip/hip_runtime.h>
#include <hip/hip_bf16.h>
#include <string.h>

#define NUM_CLASS 4096
#define HIDDEN    512
#define NGROUPS   64
#define BATCH     64

// ws layout (int offsets):
//   [0..1]            nwork[2]
//   [16..271]         work[2][128] packed (g<<20)|(ncls<<12)|c0
//   [2048..10239]     srcoff[2][4096]  rc = widx*64 + slot
//   [10240..18431]    inv[2][4096]     (scatter fallback only)
//   float idx 32768+: tmp[kh][h][widx<128][slot 64][b 64]
#define WS_NWORK 0
#define WS_WORK  16
#define WS_SRC   2048
#define WS_INV   10240
#define TMP_OFF_F 32768
#define TMP_H_STRIDE (128*4096)      // floats per (kh,h) slice
#define TMP_S_STRIDE (2*128*4096)    // floats per kh step

typedef __attribute__((ext_vector_type(8))) short short8;
typedef __attribute__((ext_vector_type(4))) float f32x4;

__device__ __forceinline__ unsigned int pack2bf(float a, float b) {
    __hip_bfloat16 ha = __float2bfloat16(a), hb = __float2bfloat16(b);
    unsigned short ua, ub;
    memcpy(&ua, &ha, 2); memcpy(&ub, &hb, 2);
    return (unsigned int)ua | ((unsigned int)ub << 16);
}

template<bool WITH_INV>
__global__ __launch_bounds__(1024) void prep_kernel(
    const int* __restrict__ co_gof, const int* __restrict__ cl_gof,
    const int* __restrict__ co_idx, const int* __restrict__ cl_idx,
    int* __restrict__ ws)
{
    __shared__ int s_starts[2][65];
    __shared__ int s_wbase[2][64];
    int tid = threadIdx.x;
    for (int v = tid; v < 2 * NUM_CLASS; v += 1024) {
        int h = v >> 12, c = v & (NUM_CLASS - 1);
        const int* gof = h ? cl_gof : co_gof;
        int g = gof[c];
        if (c == 0) { s_starts[h][0] = 0; s_starts[h][64] = NUM_CLASS; }
        else if (g != gof[c - 1]) s_starts[h][g] = c;
    }
    __syncthreads();
    if (tid < 64) {
        int lane = tid;
        for (int h = 0; h < 2; ++h) {
            int s = s_starts[h][lane], e = s_starts[h][lane + 1];
            int cnt = (e - s + 63) >> 6;
            int inc = cnt;
            #pragma unroll
            for (int d = 1; d < 64; d <<= 1) {
                int o = __shfl_up(inc, d, 64);
                if (lane >= d) inc += o;
            }
            int excl = inc - cnt;
            s_wbase[h][lane] = excl;
            for (int t = 0; t < cnt; ++t) {
                int c0 = s + t * 64;
                int ncls = min(64, e - c0);
                ws[WS_WORK + h * 128 + excl + t] = (lane << 20) | (ncls << 12) | c0;
            }
            if (lane == 63) ws[WS_NWORK + h] = inc;
        }
    }
    __syncthreads();
    for (int v = tid; v < 2 * NUM_CLASS; v += 1024) {
        int h = v >> 12, c = v & (NUM_CLASS - 1);
        const int* gof = h ? cl_gof : co_gof;
        int g = gof[c];
        int rel = c - s_starts[h][g];
        ws[WS_SRC + v] = (s_wbase[h][g] + (rel >> 6)) * 64 + (rel & 63);
        if (WITH_INV) {
            const int* idx = h ? cl_idx : co_idx;
            ws[WS_INV + h * NUM_CLASS + idx[c]] = c;
        }
    }
}

// KS in {1,2}: K split across blockIdx.z. SCATTER: direct permuted out (+bias).
template<int KS, bool SCATTER>
__global__ __launch_bounds__(256, 4) void gwl_stage1(
    const float* __restrict__ x,
    const float* __restrict__ co_W, const float* __restrict__ cl_W,
    const float* __restrict__ co_b, const float* __restrict__ cl_b,
    int* __restrict__ ws, float* __restrict__ out)
{
    int widx = blockIdx.x, h = blockIdx.y, kh = blockIdx.z;
    int nw = ws[WS_NWORK + h];
    if (widx >= nw) return;
    int packed = ws[WS_WORK + h * 128 + widx];
    int c0 = packed & 0xFFF, ncls = (packed >> 12) & 0xFF, g = packed >> 20;
    const float* Wp = h ? cl_W : co_W;
    int xrow = h * 64 + g;

    __shared__ __align__(16) unsigned char smem[18432];
    unsigned short (*Xs)[72]  = (unsigned short(*)[72])smem;
    unsigned short (*Wls)[72] = (unsigned short(*)[72])(smem + 9216);

    int tid = threadIdx.x;
    int l = tid & 63, w = tid >> 6;

    int rowq[4], kvq[4], wcl[4];
    #pragma unroll
    for (int q = 0; q < 4; ++q) {
        int v = q * 256 + tid;
        rowq[q] = v >> 4;
        kvq[q]  = v & 15;
        wcl[q]  = min(rowq[q], ncls - 1);
    }

    float4 rx[4], rw[4];
    f32x4 acc[4];
    #pragma unroll
    for (int i = 0; i < 4; ++i) acc[i] = (f32x4)(0.0f);

    const int NCH = 8 / KS;
    const int kbase = kh * (HIDDEN / KS);

#define LOADC(K0) do {                                                              \
    int k0_ = (K0);                                                                 \
    _Pragma("unroll")                                                               \
    for (int q = 0; q < 4; ++q) {                                                   \
        rx[q] = *(const float4*)(x + rowq[q] * 65536 + xrow * 512 + k0_ + kvq[q]*4);\
        rw[q] = *(const float4*)(Wp + (c0 + wcl[q]) * 512 + k0_ + kvq[q] * 4);      \
    } } while (0)

#define STOREC() do {                                                               \
    _Pragma("unroll")                                                               \
    for (int q = 0; q < 4; ++q) {                                                   \
        unsigned int x0 = pack2bf(rx[q].x, rx[q].y);                                \
        unsigned int x1 = pack2bf(rx[q].z, rx[q].w);                                \
        unsigned int w0 = pack2bf(rw[q].x, rw[q].y);                                \
        unsigned int w1 = pack2bf(rw[q].z, rw[q].w);                                \
        *(uint2*)&Xs[rowq[q]][kvq[q] * 4]  = make_uint2(x0, x1);                    \
        *(uint2*)&Wls[rowq[q]][kvq[q] * 4] = make_uint2(w0, w1);                    \
    } } while (0)

#define COMPUTEC() do {                                                             \
    _Pragma("unroll")                                                               \
    for (int kq = 0; kq < 2; ++kq) {                                                \
        int koff = kq * 32 + (l >> 4) * 8;                                          \
        short8 bfrag = *(const short8*)&Wls[w * 16 + (l & 15)][koff];               \
        _Pragma("unroll")                                                           \
        for (int i = 0; i < 4; ++i) {                                               \
            short8 afrag = *(const short8*)&Xs[16 * i + (l & 15)][koff];            \
            acc[i] = __builtin_amdgcn_mfma_f32_16x16x32_bf16(afrag, bfrag, acc[i],  \
                                                             0, 0, 0);              \
        }                                                                           \
    } } while (0)

    LOADC(kbase);
    #pragma unroll 1
    for (int t = 0; t < NCH; ++t) {
        STOREC();
        __syncthreads();
        if (t + 1 < NCH) LOADC(kbase + (t + 1) * 64);
        COMPUTEC();
        __syncthreads();
    }

    // epilogue: acc -> LDS transposed [slot][b] -> dense coalesced writes
    float (*ftile)[65] = (float(*)[65])smem;   // 64*65*4 = 16640 <= 18432
    #pragma unroll
    for (int i = 0; i < 4; ++i)
        #pragma unroll
        for (int r = 0; r < 4; ++r)
            ftile[w * 16 + (l & 15)][16 * i + (l >> 4) * 4 + r] = acc[i][r];
    __syncthreads();

    if (!SCATTER) {
        float* tile = (float*)ws + TMP_OFF_F
                    + (size_t)(kh * 2 + h) * TMP_H_STRIDE + (size_t)widx * 4096;
        #pragma unroll
        for (int p = 0; p < 4; ++p) {
            int f = p * 256 + tid;
            int slot = f >> 4, b4 = (f & 15) * 4;
            *(float4*)&tile[slot * 64 + b4] = *(const float4*)&ftile[slot][b4];
        }
    } else {
        const float* bias = h ? cl_b : co_b;
        const int*   inv  = ws + WS_INV + h * NUM_CLASS;
        float* outh = out + (size_t)h * BATCH * NUM_CLASS;
        #pragma unroll
        for (int p = 0; p < 4; ++p) {
            int f = p * 256 + tid;
            int slot = f >> 4, b4 = (f & 15) * 4;
            if (slot < ncls) {
                int c = c0 + slot;
                int oc = inv[c];
                float bb = bias[c];
                #pragma unroll
                for (int e = 0; e < 4; ++e)
                    outh[(b4 + e) * 4096 + oc] = ftile[slot][b4 + e] + bb;
            }
        }
    }
#undef LOADC
#undef STOREC
#undef COMPUTEC
}

// gather-free permute: per block = 64 output columns x 64 batch rows.
// each wave-iteration reads one contiguous 64-float (256B) tmp run per slice.
template<int KS>
__global__ __launch_bounds__(256) void gwl_permute(
    const int* __restrict__ ws,
    const float* __restrict__ co_b, const float* __restrict__ cl_b,
    const int* __restrict__ co_idx, const int* __restrict__ cl_idx,
    float* __restrict__ out)
{
    int jc = blockIdx.x;   // 0..63 : output column chunk
    int h  = blockIdx.y;   // 0..1
    const float* bias   = h ? cl_b : co_b;
    const int*   idx    = h ? cl_idx : co_idx;
    const int*   srcoff = ws + WS_SRC + h * NUM_CLASS;
    const float* tmph   = (const float*)ws + TMP_OFF_F + (size_t)h * TMP_H_STRIDE;

    __shared__ float tile[64][65];
    int tid = threadIdx.x;
    int lane = tid & 63, w = tid >> 6;

    #pragma unroll
    for (int u = 0; u < 16; ++u) {
        int jj = u * 4 + w;               // 0..63, wave-uniform
        int j  = jc * 64 + jj;
        int c  = idx[j];                  // wave-uniform scalar
        int rc = srcoff[c];               // wave-uniform scalar
        float v = bias[c];
        #pragma unroll
        for (int s = 0; s < KS; ++s)
            v += tmph[(size_t)s * TMP_S_STRIDE + (size_t)rc * 64 + lane];
        tile[lane][jj] = v;               // [b][j], stride 65 -> conflict-free
    }
    __syncthreads();

    #pragma unroll
    for (int p = 0; p < 4; ++p) {
        int f = p * 256 + tid;
        int b = f >> 4, j4 = (f & 15) * 4;
        *(float4*)&out[((size_t)h * 64 + b) * 4096 + jc * 64 + j4] =
            *(const float4*)&tile[b][j4];
    }
}

extern "C" void kernel_launch(void* const* d_in, const int* in_sizes, int n_in,
                              void* d_out, int out_size, void* d_ws, size_t ws_size,
                              hipStream_t stream)
{
    (void)in_sizes; (void)n_in; (void)out_size;
    const float* x      = (const float*)d_in[0];
    const float* co_W   = (const float*)d_in[1];
    const float* cl_W   = (const float*)d_in[2];
    const float* co_b   = (const float*)d_in[3];
    const float* cl_b   = (const float*)d_in[4];
    const int*   co_gof = (const int*)d_in[5];
    const int*   cl_gof = (const int*)d_in[6];
    const int*   co_idx = (const int*)d_in[7];
    const int*   cl_idx = (const int*)d_in[8];
    int*   ws  = (int*)d_ws;
    float* out = (float*)d_out;

    const size_t base  = (size_t)TMP_OFF_F * 4;
    const size_t slice = (size_t)TMP_S_STRIDE * 4;   // 4 MiB per kh step

    if (ws_size >= base + 2 * slice) {
        hipLaunchKernelGGL((prep_kernel<false>), dim3(1), dim3(1024), 0, stream,
                           co_gof, cl_gof, co_idx, cl_idx, ws);
        hipLaunchKernelGGL((gwl_stage1<2, false>), dim3(128, 2, 2), dim3(256), 0, stream,
                           x, co_W, cl_W, co_b, cl_b, ws, out);
        hipLaunchKernelGGL((gwl_permute<2>), dim3(64, 2), dim3(256), 0, stream,
                           ws, co_b, cl_b, co_idx, cl_idx, out);
    } else if (ws_size >= base + 1 * slice) {
        hipLaunchKernelGGL((prep_kernel<false>), dim3(1), dim3(1024), 0, stream,
                           co_gof, cl_gof, co_idx, cl_idx, ws);
        hipLaunchKernelGGL((gwl_stage1<1, false>), dim3(128, 2, 1), dim3(256), 0, stream,
                           x, co_W, cl_W, co_b, cl_b, ws, out);
        hipLaunchKernelGGL((gwl_permute<1>), dim3(64, 2), dim3(256), 0, stream,
                           ws, co_b, cl_b, co_idx, cl_idx, out);
    } else {
        hipLaunchKernelGGL((prep_kernel<true>), dim3(1), dim3(1024), 0, stream,
                           co_gof, cl_gof, co_idx, cl_idx, ws);
        hipLaunchKernelGGL((gwl_stage1<1, true>), dim3(128, 2, 1), dim3(256), 0, stream,
                           x, co_W, cl_W, co_b, cl_b, ws, out);
    }
}

// Round 6
// 23.795 us; speedup vs baseline: 1.5839x; 1.0469x over previous
//
#include <hip/hip_runtime.h>
#include <hip/hip_bf16.h>
#include <string.h>

#define NUM_CLASS 4096
#define HIDDEN    512
#define NGROUPS   64
#define BATCH     64

// ws layout (int offsets):
//   [0..1]            nwork[2]
//   [16..271]         work[2][128] packed (g<<20)|(ncls<<12)|c0
//   [2048..10239]     srcoff[2][4096]  rc = widx*64 + slot
//   [10240..18431]    inv[2][4096]     (scatter fallback only)
//   float idx 32768+: tmp[kh][h][widx<128][slot 64][b 64]
#define WS_NWORK 0
#define WS_WORK  16
#define WS_SRC   2048
#define WS_INV   10240
#define TMP_OFF_F 32768
#define TMP_H_STRIDE (128*4096)      // floats per (kh,h) slice
#define TMP_S_STRIDE (2*128*4096)    // floats per kh step

typedef __attribute__((ext_vector_type(8))) short short8;
typedef __attribute__((ext_vector_type(4))) float f32x4;

__device__ __forceinline__ unsigned int pack2bf(float a, float b) {
    __hip_bfloat16 ha = __float2bfloat16(a), hb = __float2bfloat16(b);
    unsigned short ua, ub;
    memcpy(&ua, &ha, 2); memcpy(&ub, &hb, 2);
    return (unsigned int)ua | ((unsigned int)ub << 16);
}

template<bool WITH_INV>
__global__ __launch_bounds__(1024) void prep_kernel(
    const int* __restrict__ co_gof, const int* __restrict__ cl_gof,
    const int* __restrict__ co_idx, const int* __restrict__ cl_idx,
    int* __restrict__ ws)
{
    __shared__ int s_starts[2][65];
    __shared__ int s_wbase[2][64];
    int tid = threadIdx.x;
    for (int v = tid; v < 2 * NUM_CLASS; v += 1024) {
        int h = v >> 12, c = v & (NUM_CLASS - 1);
        const int* gof = h ? cl_gof : co_gof;
        int g = gof[c];
        if (c == 0) { s_starts[h][0] = 0; s_starts[h][64] = NUM_CLASS; }
        else if (g != gof[c - 1]) s_starts[h][g] = c;
    }
    __syncthreads();
    if (tid < 64) {
        int lane = tid;
        for (int h = 0; h < 2; ++h) {
            int s = s_starts[h][lane], e = s_starts[h][lane + 1];
            int cnt = (e - s + 63) >> 6;
            int inc = cnt;
            #pragma unroll
            for (int d = 1; d < 64; d <<= 1) {
                int o = __shfl_up(inc, d, 64);
                if (lane >= d) inc += o;
            }
            int excl = inc - cnt;
            s_wbase[h][lane] = excl;
            for (int t = 0; t < cnt; ++t) {
                int c0 = s + t * 64;
                int ncls = min(64, e - c0);
                ws[WS_WORK + h * 128 + excl + t] = (lane << 20) | (ncls << 12) | c0;
            }
            if (lane == 63) ws[WS_NWORK + h] = inc;
        }
    }
    __syncthreads();
    for (int v = tid; v < 2 * NUM_CLASS; v += 1024) {
        int h = v >> 12, c = v & (NUM_CLASS - 1);
        const int* gof = h ? cl_gof : co_gof;
        int g = gof[c];
        int rel = c - s_starts[h][g];
        ws[WS_SRC + v] = (s_wbase[h][g] + (rel >> 6)) * 64 + (rel & 63);
        if (WITH_INV) {
            const int* idx = h ? cl_idx : co_idx;
            ws[WS_INV + h * NUM_CLASS + idx[c]] = c;
        }
    }
}

// KS in {1,2}: K split. 1-D grid with XCD-chunked bijective swizzle.
// 2-deep register prefetch + double-buffered LDS, one barrier per chunk.
template<int KS, bool SCATTER>
__global__ __launch_bounds__(256, 2) void gwl_stage1(
    const float* __restrict__ x,
    const float* __restrict__ co_W, const float* __restrict__ cl_W,
    const float* __restrict__ co_b, const float* __restrict__ cl_b,
    int* __restrict__ ws, float* __restrict__ out)
{
    // nblk = 128*2*KS, divisible by 8; chunked XCD swizzle
    const int nblk = 128 * 2 * KS;
    const int chunk = nblk >> 3;
    int bid = blockIdx.x;
    int swz = (bid & 7) * chunk + (bid >> 3);
    int widx = swz & 127;
    int hk   = swz >> 7;
    int h    = hk & 1;
    int kh   = hk >> 1;

    int nw = ws[WS_NWORK + h];
    if (widx >= nw) return;
    int packed = ws[WS_WORK + h * 128 + widx];
    int c0 = packed & 0xFFF, ncls = (packed >> 12) & 0xFF, g = packed >> 20;
    const float* Wp = h ? cl_W : co_W;
    int xrow = h * 64 + g;

    __shared__ __align__(16) unsigned char smem[2][18432];

    int tid = threadIdx.x;
    int l = tid & 63, w = tid >> 6;

    int rowq[4], kvq[4], wcl[4];
    #pragma unroll
    for (int q = 0; q < 4; ++q) {
        int v = q * 256 + tid;
        rowq[q] = v >> 4;
        kvq[q]  = v & 15;
        wcl[q]  = min(rowq[q], ncls - 1);
    }

    float4 rxA[4], rwA[4], rxB[4], rwB[4];
    f32x4 acc[4];
    #pragma unroll
    for (int i = 0; i < 4; ++i) acc[i] = (f32x4)(0.0f);

    const int NCH = 8 / KS;
    const int kbase = kh * (HIDDEN / KS);

#define LOADC(T, RX, RW) do {                                                       \
    int k0_ = kbase + (T) * 64;                                                     \
    _Pragma("unroll")                                                               \
    for (int q = 0; q < 4; ++q) {                                                   \
        RX[q] = *(const float4*)(x + rowq[q] * 65536 + xrow * 512 + k0_ + kvq[q]*4);\
        RW[q] = *(const float4*)(Wp + (c0 + wcl[q]) * 512 + k0_ + kvq[q] * 4);      \
    } } while (0)

#define STOREC(BUF, RX, RW) do {                                                    \
    unsigned short (*Xs_)[72]  = (unsigned short(*)[72])smem[BUF];                  \
    unsigned short (*Wls_)[72] = (unsigned short(*)[72])(smem[BUF] + 9216);         \
    _Pragma("unroll")                                                               \
    for (int q = 0; q < 4; ++q) {                                                   \
        unsigned int x0 = pack2bf(RX[q].x, RX[q].y);                                \
        unsigned int x1 = pack2bf(RX[q].z, RX[q].w);                                \
        unsigned int w0 = pack2bf(RW[q].x, RW[q].y);                                \
        unsigned int w1 = pack2bf(RW[q].z, RW[q].w);                                \
        *(uint2*)&Xs_[rowq[q]][kvq[q] * 4]  = make_uint2(x0, x1);                   \
        *(uint2*)&Wls_[rowq[q]][kvq[q] * 4] = make_uint2(w0, w1);                   \
    } } while (0)

#define COMPUTEC(BUF) do {                                                          \
    unsigned short (*Xs_)[72]  = (unsigned short(*)[72])smem[BUF];                  \
    unsigned short (*Wls_)[72] = (unsigned short(*)[72])(smem[BUF] + 9216);         \
    _Pragma("unroll")                                                               \
    for (int kq = 0; kq < 2; ++kq) {                                                \
        int koff = kq * 32 + (l >> 4) * 8;                                          \
        short8 bfrag = *(const short8*)&Wls_[w * 16 + (l & 15)][koff];              \
        _Pragma("unroll")                                                           \
        for (int i = 0; i < 4; ++i) {                                               \
            short8 afrag = *(const short8*)&Xs_[16 * i + (l & 15)][koff];           \
            acc[i] = __builtin_amdgcn_mfma_f32_16x16x32_bf16(afrag, bfrag, acc[i],  \
                                                             0, 0, 0);              \
        }                                                                           \
    } } while (0)

    LOADC(0, rxA, rwA);
    LOADC(1, rxB, rwB);
    STOREC(0, rxA, rwA);
    __syncthreads();
    #pragma unroll
    for (int t = 0; t < NCH; ++t) {
        if (t + 2 < NCH) {
            if (t & 1) LOADC(t + 2, rxB, rwB);
            else       LOADC(t + 2, rxA, rwA);
        }
        if (t + 1 < NCH) {
            if (t & 1) STOREC((t + 1) & 1, rxA, rwA);
            else       STOREC((t + 1) & 1, rxB, rwB);
        }
        COMPUTEC(t & 1);
        __syncthreads();
    }

    // epilogue: acc -> LDS transposed [slot][b] -> dense coalesced writes
    float (*ftile)[65] = (float(*)[65])smem[0];   // 64*65*4 = 16640 <= 18432
    #pragma unroll
    for (int i = 0; i < 4; ++i)
        #pragma unroll
        for (int r = 0; r < 4; ++r)
            ftile[w * 16 + (l & 15)][16 * i + (l >> 4) * 4 + r] = acc[i][r];
    __syncthreads();

    if (!SCATTER) {
        float* tile = (float*)ws + TMP_OFF_F
                    + (size_t)(kh * 2 + h) * TMP_H_STRIDE + (size_t)widx * 4096;
        #pragma unroll
        for (int p = 0; p < 4; ++p) {
            int f = p * 256 + tid;
            int slot = f >> 4, b4 = (f & 15) * 4;
            *(float4*)&tile[slot * 64 + b4] = *(const float4*)&ftile[slot][b4];
        }
    } else {
        const float* bias = h ? cl_b : co_b;
        const int*   inv  = ws + WS_INV + h * NUM_CLASS;
        float* outh = out + (size_t)h * BATCH * NUM_CLASS;
        #pragma unroll
        for (int p = 0; p < 4; ++p) {
            int f = p * 256 + tid;
            int slot = f >> 4, b4 = (f & 15) * 4;
            if (slot < ncls) {
                int c = c0 + slot;
                int oc = inv[c];
                float bb = bias[c];
                #pragma unroll
                for (int e = 0; e < 4; ++e)
                    outh[(b4 + e) * 4096 + oc] = ftile[slot][b4 + e] + bb;
            }
        }
    }
#undef LOADC
#undef STOREC
#undef COMPUTEC
}

// gather-free permute: per block = 64 output columns x 64 batch rows.
// each wave-iteration reads one contiguous 64-float (256B) tmp run per slice.
template<int KS>
__global__ __launch_bounds__(256) void gwl_permute(
    const int* __restrict__ ws,
    const float* __restrict__ co_b, const float* __restrict__ cl_b,
    const int* __restrict__ co_idx, const int* __restrict__ cl_idx,
    float* __restrict__ out)
{
    int jc = blockIdx.x;   // 0..63 : output column chunk
    int h  = blockIdx.y;   // 0..1
    const float* bias   = h ? cl_b : co_b;
    const int*   idx    = h ? cl_idx : co_idx;
    const int*   srcoff = ws + WS_SRC + h * NUM_CLASS;
    const float* tmph   = (const float*)ws + TMP_OFF_F + (size_t)h * TMP_H_STRIDE;

    __shared__ float tile[64][65];
    int tid = threadIdx.x;
    int lane = tid & 63, w = tid >> 6;

    #pragma unroll
    for (int u = 0; u < 16; ++u) {
        int jj = u * 4 + w;               // 0..63, wave-uniform
        int j  = jc * 64 + jj;
        int c  = idx[j];                  // wave-uniform scalar
        int rc = srcoff[c];               // wave-uniform scalar
        float v = bias[c];
        #pragma unroll
        for (int s = 0; s < KS; ++s)
            v += tmph[(size_t)s * TMP_S_STRIDE + (size_t)rc * 64 + lane];
        tile[lane][jj] = v;               // [b][j], stride 65 -> conflict-free
    }
    __syncthreads();

    #pragma unroll
    for (int p = 0; p < 4; ++p) {
        int f = p * 256 + tid;
        int b = f >> 4, j4 = (f & 15) * 4;
        *(float4*)&out[((size_t)h * 64 + b) * 4096 + jc * 64 + j4] =
            *(const float4*)&tile[b][j4];
    }
}

extern "C" void kernel_launch(void* const* d_in, const int* in_sizes, int n_in,
                              void* d_out, int out_size, void* d_ws, size_t ws_size,
                              hipStream_t stream)
{
    (void)in_sizes; (void)n_in; (void)out_size;
    const float* x      = (const float*)d_in[0];
    const float* co_W   = (const float*)d_in[1];
    const float* cl_W   = (const float*)d_in[2];
    const float* co_b   = (const float*)d_in[3];
    const float* cl_b   = (const float*)d_in[4];
    const int*   co_gof = (const int*)d_in[5];
    const int*   cl_gof = (const int*)d_in[6];
    const int*   co_idx = (const int*)d_in[7];
    const int*   cl_idx = (const int*)d_in[8];
    int*   ws  = (int*)d_ws;
    float* out = (float*)d_out;

    const size_t base  = (size_t)TMP_OFF_F * 4;
    const size_t slice = (size_t)TMP_S_STRIDE * 4;   // 4 MiB per kh step

    if (ws_size >= base + 2 * slice) {
        hipLaunchKernelGGL((prep_kernel<false>), dim3(1), dim3(1024), 0, stream,
                           co_gof, cl_gof, co_idx, cl_idx, ws);
        hipLaunchKernelGGL((gwl_stage1<2, false>), dim3(512), dim3(256), 0, stream,
                           x, co_W, cl_W, co_b, cl_b, ws, out);
        hipLaunchKernelGGL((gwl_permute<2>), dim3(64, 2), dim3(256), 0, stream,
                           ws, co_b, cl_b, co_idx, cl_idx, out);
    } else if (ws_size >= base + 1 * slice) {
        hipLaunchKernelGGL((prep_kernel<false>), dim3(1), dim3(1024), 0, stream,
                           co_gof, cl_gof, co_idx, cl_idx, ws);
        hipLaunchKernelGGL((gwl_stage1<1, false>), dim3(256), dim3(256), 0, stream,
                           x, co_W, cl_W, co_b, cl_b, ws, out);
        hipLaunchKernelGGL((gwl_permute<1>), dim3(64, 2), dim3(256), 0, stream,
                           ws, co_b, cl_b, co_idx, cl_idx, out);
    } else {
        hipLaunchKernelGGL((prep_kernel<true>), dim3(1), dim3(1024), 0, stream,
                           co_gof, cl_gof, co_idx, cl_idx, ws);
        hipLaunchKernelGGL((gwl_stage1<1, true>), dim3(256), dim3(256), 0, stream,
                           x, co_W, cl_W, co_b, cl_b, ws, out);
    }
}

// Round 7
// 22.967 us; speedup vs baseline: 1.6410x; 1.0360x over previous
//
#include <hip/hip_runtime.h>
#include <hip/hip_bf16.h>
#include <string.h>

#define NUM_CLASS 4096
#define HIDDEN    512
#define NGROUPS   64
#define BATCH     64

// ws layout (int offsets):
//   [0..1]            nwork[2]
//   [16..271]         work[2][128] packed (g<<20)|(ncls<<12)|c0
//   [10240..18431]    inv[2][4096]     (scatter fallback only)
//   float idx 16384+: tmp[kh][h][class 4096][b 64]
#define WS_NWORK 0
#define WS_WORK  16
#define WS_INV   10240
#define TMP_OFF_F 16384
#define TMP_H_STRIDE (4096*64)       // floats per (kh,h) slice (1 MiB)
#define TMP_S_STRIDE (2*4096*64)     // floats per kh step (2 MiB)

typedef __attribute__((ext_vector_type(8))) short short8;
typedef __attribute__((ext_vector_type(4))) float f32x4;

__device__ __forceinline__ unsigned int pack2bf(float a, float b) {
    __hip_bfloat16 ha = __float2bfloat16(a), hb = __float2bfloat16(b);
    unsigned short ua, ub;
    memcpy(&ua, &ha, 2); memcpy(&ub, &hb, 2);
    return (unsigned int)ua | ((unsigned int)ub << 16);
}

template<bool WITH_INV>
__global__ __launch_bounds__(1024) void prep_kernel(
    const int* __restrict__ co_gof, const int* __restrict__ cl_gof,
    const int* __restrict__ co_idx, const int* __restrict__ cl_idx,
    int* __restrict__ ws)
{
    __shared__ int s_starts[2][65];
    int tid = threadIdx.x;
    for (int v = tid; v < 2 * NUM_CLASS; v += 1024) {
        int h = v >> 12, c = v & (NUM_CLASS - 1);
        const int* gof = h ? cl_gof : co_gof;
        int g = gof[c];
        if (c == 0) { s_starts[h][0] = 0; s_starts[h][64] = NUM_CLASS; }
        else if (g != gof[c - 1]) s_starts[h][g] = c;
        if (WITH_INV) {
            const int* idx = h ? cl_idx : co_idx;
            ws[WS_INV + h * NUM_CLASS + idx[c]] = c;
        }
    }
    __syncthreads();
    if (tid < 64) {
        int lane = tid;
        for (int h = 0; h < 2; ++h) {
            int s = s_starts[h][lane], e = s_starts[h][lane + 1];
            int cnt = (e - s + 63) >> 6;
            int inc = cnt;
            #pragma unroll
            for (int d = 1; d < 64; d <<= 1) {
                int o = __shfl_up(inc, d, 64);
                if (lane >= d) inc += o;
            }
            int excl = inc - cnt;
            for (int t = 0; t < cnt; ++t) {
                int c0 = s + t * 64;
                int ncls = min(64, e - c0);
                ws[WS_WORK + h * 128 + excl + t] = (lane << 20) | (ncls << 12) | c0;
            }
            if (lane == 63) ws[WS_NWORK + h] = inc;
        }
    }
}

// KS in {1,2,4}: K split. 1-D grid with XCD-chunked bijective swizzle.
// 2-deep register prefetch + double-buffered LDS, one barrier per chunk.
template<int KS, bool SCATTER>
__global__ __launch_bounds__(256, 4) void gwl_stage1(
    const float* __restrict__ x,
    const float* __restrict__ co_W, const float* __restrict__ cl_W,
    const float* __restrict__ co_b, const float* __restrict__ cl_b,
    int* __restrict__ ws, float* __restrict__ out)
{
    // nblk = 128*2*KS, divisible by 8; chunked XCD swizzle
    const int nblk = 128 * 2 * KS;
    const int chunk = nblk >> 3;
    int bid = blockIdx.x;
    int swz = (bid & 7) * chunk + (bid >> 3);
    int widx = swz & 127;
    int hk   = swz >> 7;
    int h    = hk & 1;
    int kh   = hk >> 1;

    int nw = ws[WS_NWORK + h];
    if (widx >= nw) return;
    int packed = ws[WS_WORK + h * 128 + widx];
    int c0 = packed & 0xFFF, ncls = (packed >> 12) & 0xFF, g = packed >> 20;
    const float* Wp = h ? cl_W : co_W;
    int xrow = h * 64 + g;

    __shared__ __align__(16) unsigned char smem[2][18432];

    int tid = threadIdx.x;
    int l = tid & 63, w = tid >> 6;

    int rowq[4], kvq[4], wcl[4];
    #pragma unroll
    for (int q = 0; q < 4; ++q) {
        int v = q * 256 + tid;
        rowq[q] = v >> 4;
        kvq[q]  = v & 15;
        wcl[q]  = min(rowq[q], ncls - 1);
    }

    float4 rxA[4], rwA[4], rxB[4], rwB[4];
    f32x4 acc[4];
    #pragma unroll
    for (int i = 0; i < 4; ++i) acc[i] = (f32x4)(0.0f);

    const int NCH = 8 / KS;
    const int kbase = kh * (HIDDEN / KS);

#define LOADC(T, RX, RW) do {                                                       \
    int k0_ = kbase + (T) * 64;                                                     \
    _Pragma("unroll")                                                               \
    for (int q = 0; q < 4; ++q) {                                                   \
        RX[q] = *(const float4*)(x + rowq[q] * 65536 + xrow * 512 + k0_ + kvq[q]*4);\
        RW[q] = *(const float4*)(Wp + (c0 + wcl[q]) * 512 + k0_ + kvq[q] * 4);      \
    } } while (0)

#define STOREC(BUF, RX, RW) do {                                                    \
    unsigned short (*Xs_)[72]  = (unsigned short(*)[72])smem[BUF];                  \
    unsigned short (*Wls_)[72] = (unsigned short(*)[72])(smem[BUF] + 9216);         \
    _Pragma("unroll")                                                               \
    for (int q = 0; q < 4; ++q) {                                                   \
        unsigned int x0 = pack2bf(RX[q].x, RX[q].y);                                \
        unsigned int x1 = pack2bf(RX[q].z, RX[q].w);                                \
        unsigned int w0 = pack2bf(RW[q].x, RW[q].y);                                \
        unsigned int w1 = pack2bf(RW[q].z, RW[q].w);                                \
        *(uint2*)&Xs_[rowq[q]][kvq[q] * 4]  = make_uint2(x0, x1);                   \
        *(uint2*)&Wls_[rowq[q]][kvq[q] * 4] = make_uint2(w0, w1);                   \
    } } while (0)

#define COMPUTEC(BUF) do {                                                          \
    unsigned short (*Xs_)[72]  = (unsigned short(*)[72])smem[BUF];                  \
    unsigned short (*Wls_)[72] = (unsigned short(*)[72])(smem[BUF] + 9216);         \
    _Pragma("unroll")                                                               \
    for (int kq = 0; kq < 2; ++kq) {                                                \
        int koff = kq * 32 + (l >> 4) * 8;                                          \
        short8 bfrag = *(const short8*)&Wls_[w * 16 + (l & 15)][koff];              \
        _Pragma("unroll")                                                           \
        for (int i = 0; i < 4; ++i) {                                               \
            short8 afrag = *(const short8*)&Xs_[16 * i + (l & 15)][koff];           \
            acc[i] = __builtin_amdgcn_mfma_f32_16x16x32_bf16(afrag, bfrag, acc[i],  \
                                                             0, 0, 0);              \
        }                                                                           \
    } } while (0)

    LOADC(0, rxA, rwA);
    if (NCH > 1) LOADC(1, rxB, rwB);
    STOREC(0, rxA, rwA);
    __syncthreads();
    #pragma unroll
    for (int t = 0; t < NCH; ++t) {
        if (t + 2 < NCH) {
            if (t & 1) LOADC(t + 2, rxB, rwB);
            else       LOADC(t + 2, rxA, rwA);
        }
        if (t + 1 < NCH) {
            if (t & 1) STOREC((t + 1) & 1, rxA, rwA);
            else       STOREC((t + 1) & 1, rxB, rwB);
        }
        COMPUTEC(t & 1);
        __syncthreads();
    }

    // epilogue: acc -> LDS transposed [slot][b] -> dense coalesced writes
    float (*ftile)[65] = (float(*)[65])smem[0];   // 64*65*4 = 16640 <= 18432
    #pragma unroll
    for (int i = 0; i < 4; ++i)
        #pragma unroll
        for (int r = 0; r < 4; ++r)
            ftile[w * 16 + (l & 15)][16 * i + (l >> 4) * 4 + r] = acc[i][r];
    __syncthreads();

    if (!SCATTER) {
        // class-indexed tmp: rows are global class ids (contiguous in chunk)
        float* tmph = (float*)ws + TMP_OFF_F + (size_t)(kh * 2 + h) * TMP_H_STRIDE;
        #pragma unroll
        for (int p = 0; p < 4; ++p) {
            int f = p * 256 + tid;
            int slot = f >> 4, b4 = (f & 15) * 4;
            if (slot < ncls)
                *(float4*)&tmph[(size_t)(c0 + slot) * 64 + b4] =
                    *(const float4*)&ftile[slot][b4];
        }
    } else {
        const float* bias = h ? cl_b : co_b;
        const int*   inv  = ws + WS_INV + h * NUM_CLASS;
        float* outh = out + (size_t)h * BATCH * NUM_CLASS;
        #pragma unroll
        for (int p = 0; p < 4; ++p) {
            int f = p * 256 + tid;
            int slot = f >> 4, b4 = (f & 15) * 4;
            if (slot < ncls) {
                int c = c0 + slot;
                int oc = inv[c];
                float bb = bias[c];
                #pragma unroll
                for (int e = 0; e < 4; ++e)
                    outh[(b4 + e) * 4096 + oc] = ftile[slot][b4 + e] + bb;
            }
        }
    }
#undef LOADC
#undef STOREC
#undef COMPUTEC
}

// gather-free permute: per block = 64 output columns x 64 batch rows.
// each wave-iteration reads KS contiguous 64-float (256B) tmp runs.
template<int KS>
__global__ __launch_bounds__(256) void gwl_permute(
    const int* __restrict__ ws,
    const float* __restrict__ co_b, const float* __restrict__ cl_b,
    const int* __restrict__ co_idx, const int* __restrict__ cl_idx,
    float* __restrict__ out)
{
    int jc = blockIdx.x;   // 0..63 : output column chunk
    int h  = blockIdx.y;   // 0..1
    const float* bias = h ? cl_b : co_b;
    const int*   idx  = h ? cl_idx : co_idx;
    const float* tmph = (const float*)ws + TMP_OFF_F + (size_t)h * TMP_H_STRIDE;

    __shared__ float tile[64][65];
    int tid = threadIdx.x;
    int lane = tid & 63, w = tid >> 6;

    #pragma unroll
    for (int u = 0; u < 16; ++u) {
        int jj = u * 4 + w;               // 0..63, wave-uniform
        int j  = jc * 64 + jj;
        int c  = idx[j];                  // wave-uniform scalar
        float v = bias[c];
        #pragma unroll
        for (int s = 0; s < KS; ++s)
            v += tmph[(size_t)s * TMP_S_STRIDE + (size_t)c * 64 + lane];
        tile[lane][jj] = v;               // [b][j], stride 65 -> conflict-free
    }
    __syncthreads();

    #pragma unroll
    for (int p = 0; p < 4; ++p) {
        int f = p * 256 + tid;
        int b = f >> 4, j4 = (f & 15) * 4;
        *(float4*)&out[((size_t)h * 64 + b) * 4096 + jc * 64 + j4] =
            *(const float4*)&tile[b][j4];
    }
}

extern "C" void kernel_launch(void* const* d_in, const int* in_sizes, int n_in,
                              void* d_out, int out_size, void* d_ws, size_t ws_size,
                              hipStream_t stream)
{
    (void)in_sizes; (void)n_in; (void)out_size;
    const float* x      = (const float*)d_in[0];
    const float* co_W   = (const float*)d_in[1];
    const float* cl_W   = (const float*)d_in[2];
    const float* co_b   = (const float*)d_in[3];
    const float* cl_b   = (const float*)d_in[4];
    const int*   co_gof = (const int*)d_in[5];
    const int*   cl_gof = (const int*)d_in[6];
    const int*   co_idx = (const int*)d_in[7];
    const int*   cl_idx = (const int*)d_in[8];
    int*   ws  = (int*)d_ws;
    float* out = (float*)d_out;

    const size_t base  = (size_t)TMP_OFF_F * 4;
    const size_t slice = (size_t)TMP_S_STRIDE * 4;   // 2 MiB per kh step

    if (ws_size >= base + 4 * slice) {
        hipLaunchKernelGGL((prep_kernel<false>), dim3(1), dim3(1024), 0, stream,
                           co_gof, cl_gof, co_idx, cl_idx, ws);
        hipLaunchKernelGGL((gwl_stage1<4, false>), dim3(1024), dim3(256), 0, stream,
                           x, co_W, cl_W, co_b, cl_b, ws, out);
        hipLaunchKernelGGL((gwl_permute<4>), dim3(64, 2), dim3(256), 0, stream,
                           ws, co_b, cl_b, co_idx, cl_idx, out);
    } else if (ws_size >= base + 2 * slice) {
        hipLaunchKernelGGL((prep_kernel<false>), dim3(1), dim3(1024), 0, stream,
                           co_gof, cl_gof, co_idx, cl_idx, ws);
        hipLaunchKernelGGL((gwl_stage1<2, false>), dim3(512), dim3(256), 0, stream,
                           x, co_W, cl_W, co_b, cl_b, ws, out);
        hipLaunchKernelGGL((gwl_permute<2>), dim3(64, 2), dim3(256), 0, stream,
                           ws, co_b, cl_b, co_idx, cl_idx, out);
    } else if (ws_size >= base + 1 * slice) {
        hipLaunchKernelGGL((prep_kernel<false>), dim3(1), dim3(1024), 0, stream,
                           co_gof, cl_gof, co_idx, cl_idx, ws);
        hipLaunchKernelGGL((gwl_stage1<1, false>), dim3(256), dim3(256), 0, stream,
                           x, co_W, cl_W, co_b, cl_b, ws, out);
        hipLaunchKernelGGL((gwl_permute<1>), dim3(64, 2), dim3(256), 0, stream,
                           ws, co_b, cl_b, co_idx, cl_idx, out);
    } else {
        hipLaunchKernelGGL((prep_kernel<true>), dim3(1), dim3(1024), 0, stream,
                           co_gof, cl_gof, co_idx, cl_idx, ws);
        hipLaunchKernelGGL((gwl_stage1<1, true>), dim3(256), dim3(256), 0, stream,
                           x, co_W, cl_W, co_b, cl_b, ws, out);
    }
}